// Round 12
// baseline (82.564 us; speedup 1.0000x reference)
//
#include <hip/hip_runtime.h>

#define NN 50
#define D 64
#define GRP 10

typedef unsigned int uint32;
typedef unsigned short ushort16;

__device__ __forceinline__ float wave_sum64(float x) {
#pragma unroll
  for (int off = 32; off > 0; off >>= 1)
    x += __shfl_xor(x, off, 64);
  return x;
}

__device__ __forceinline__ float readlane_f(float v, int l) {
  return __uint_as_float(__builtin_amdgcn_readlane(__float_as_uint(v), l));
}

__device__ __forceinline__ ushort16 f32_to_bf16(float f) {
  uint32 u = __float_as_uint(f);
  u += 0x7FFF + ((u >> 16) & 1);          // round-to-nearest-even
  return (ushort16)(u >> 16);
}
__device__ __forceinline__ float bf16_to_f32(ushort16 h) {
  return __uint_as_float(((uint32)h) << 16);
}

// ============ P: proj[e] = dot(ent[e], Wn); ent_bf = bf16(ent) ==============
__global__ __launch_bounds__(256, 4) void ent_proj(
    const float* __restrict__ ent_tab, const float* __restrict__ attn_W,
    float* __restrict__ proj, ushort16* __restrict__ ent_bf, int rows)
{
  const int  lane = threadIdx.x & 63;
  const long wave = (long)blockIdx.x * 4 + (threadIdx.x >> 6);
  const long base = wave * GRP;
  if (base >= rows) return;
  const float Wn = attn_W[D + lane];
  float v[GRP];
#pragma unroll
  for (int i = 0; i < GRP; ++i) {
    long r = base + i; if (r > rows - 1) r = rows - 1;
    v[i] = ent_tab[r * D + lane];           // coalesced, contiguous rows
  }
  float s[GRP];
#pragma unroll
  for (int i = 0; i < GRP; ++i)
    s[i] = wave_sum64(v[i] * Wn);           // 10 independent butterfly chains
#pragma unroll
  for (int i = 0; i < GRP; ++i) {
    const long r = base + i;
    if (r < rows) ent_bf[r * D + lane] = f32_to_bf16(v[i]);
  }
  if (lane == 0) {
#pragma unroll
    for (int i = 0; i < GRP; ++i)
      if (base + i < rows) proj[base + i] = s[i];
  }
}

// ================== fused attn + MLP, deep-prefetch gathers ==================
__device__ __forceinline__ void load_grp_bf(float (&buf)[GRP],
                                            const int* __restrict__ adjb,
                                            const ushort16* __restrict__ ent_bf,
                                            int g, int lane) {
#pragma unroll
  for (int i = 0; i < GRP; ++i) {
    int t = adjb[g * GRP + i];              // wave-uniform -> s_load
    t = t < 0 ? 0 : t;
    buf[i] = bf16_to_f32(ent_bf[(long)t * D + lane]);   // 128B coalesced row
  }
}

__device__ __forceinline__ void acc_grp(const float (&buf)[GRP], float e, int g,
                                        float& na0, float& na1) {
#pragma unroll
  for (int i = 0; i < GRP; ++i) {
    const float w = readlane_f(e, g * GRP + i);   // compile-time lane index
    if (i & 1) na1 = fmaf(w, buf[i], na1);
    else       na0 = fmaf(w, buf[i], na0);
  }
}

__global__ __launch_bounds__(256, 4) void kgat_fused(
    const int* __restrict__ user_idx, const int* __restrict__ item_idx,
    const int* __restrict__ adj,
    const float* __restrict__ user_tab, const float* __restrict__ item_tab,
    const ushort16* __restrict__ ent_bf, const float* __restrict__ proj,
    const float* __restrict__ attn_W, const float* __restrict__ attn_b,
    const float* __restrict__ W1, const float* __restrict__ b1,
    const float* __restrict__ W2, const float* __restrict__ b2,
    const float* __restrict__ cW, const float* __restrict__ cb,
    const float* __restrict__ oW, const float* __restrict__ ob,
    float* __restrict__ out, int B)
{
  __shared__ __align__(16) float s_act[4 * D];   // per-wave activation bcast
  __shared__ __align__(16) float s_itm[4 * D];   // per-wave item bcast

  const int lane = threadIdx.x & 63;
  const int wv   = threadIdx.x >> 6;
  const int b    = blockIdx.x * 4 + wv;
  if (b >= B) return;
  float* sa = s_act + wv * D;
  float* si = s_itm + wv * D;

  const int* adjb = adj + (long)b * NN;

  // ---- issue score-path loads FIRST (oldest in vmcnt order, so the math
  //      below can start while the 50 row-gathers are still in flight) ----
  const int myn = lane < NN ? lane : NN - 1;
  int mi = adjb[myn]; mi = mi < 0 ? 0 : mi;       // per-lane coalesced 200B
  const float pj   = proj[mi];                    // per-lane gather (L2-hot)
  const float user = user_tab[(long)user_idx[b] * D + lane];
  const float item = item_tab[(long)item_idx[b] * D + lane];

  // ---- deep prefetch: ALL 50 neighbor rows issued now (one round trip) ----
  float G0[GRP], G1[GRP], G2[GRP], G3[GRP], G4[GRP];
  load_grp_bf(G0, adjb, ent_bf, 0, lane);
  load_grp_bf(G1, adjb, ent_bf, 1, lane);
  load_grp_bf(G2, adjb, ent_bf, 2, lane);
  load_grp_bf(G3, adjb, ent_bf, 3, lane);
  load_grp_bf(G4, adjb, ent_bf, 4, lane);

  // ---- scores while gathers fly ----
  si[lane] = item;                                // wave-private, no barrier
  const float base = wave_sum64(item * attn_W[lane]) + attn_b[0];  // uniform
  float s = pj + base;
  s = s > 0.f ? s : 0.2f * s;                     // leaky_relu(0.2)
  // fixed-max softmax: scores are leaky_relu of ~unit-variance dots, bounded
  // well below 8 -> exp(s-8) can't overflow, denom can't underflow to 0.
  const float e = (lane < NN) ? __expf(s - 8.0f) : 0.f;
  const float denom = wave_sum64(e);

  // ---- weighted sum over the prefetched rows ----
  float na0 = 0.f, na1 = 0.f;
  acc_grp(G0, e, 0, na0, na1);
  acc_grp(G1, e, 1, na0, na1);
  acc_grp(G2, e, 2, na0, na1);
  acc_grp(G3, e, 3, na0, na1);
  acc_grp(G4, e, 4, na0, na1);
  const float na = (na0 + na1) / denom;

  // ---- h = relu(na @ W1 + b1): activations broadcast from LDS (b128,
  //      uniform address = conflict-free), weights coalesced from global ----
  sa[lane] = na;
  float h0 = b1[lane], h1 = 0.f, h2 = 0.f, h3 = 0.f;
#pragma unroll
  for (int d = 0; d < D; d += 4) {
    const float4 c = *(const float4*)(sa + d);
    h0 = fmaf(c.x, W1[(d + 0) * D + lane], h0);
    h1 = fmaf(c.y, W1[(d + 1) * D + lane], h1);
    h2 = fmaf(c.z, W1[(d + 2) * D + lane], h2);
    h3 = fmaf(c.w, W1[(d + 3) * D + lane], h3);
  }
  const float h = fmaxf((h0 + h1) + (h2 + h3), 0.f);

  // ---- r = h @ W2 + b2 ----
  sa[lane] = h;
  float r0 = b2[lane], r1 = 0.f, r2 = 0.f, r3 = 0.f;
#pragma unroll
  for (int d = 0; d < D; d += 4) {
    const float4 c = *(const float4*)(sa + d);
    r0 = fmaf(c.x, W2[(d + 0) * D + lane], r0);
    r1 = fmaf(c.y, W2[(d + 1) * D + lane], r1);
    r2 = fmaf(c.z, W2[(d + 2) * D + lane], r2);
    r3 = fmaf(c.w, W2[(d + 3) * D + lane], r3);
  }
  const float r = (r0 + r1) + (r2 + r3);

  // ---- f = relu([item, r] @ cW + cb) ----
  sa[lane] = r;
  float f0 = cb[lane], f1 = 0.f, f2 = 0.f, f3 = 0.f;
#pragma unroll
  for (int k = 0; k < D; k += 4) {
    const float4 ci = *(const float4*)(si + k);
    f0 = fmaf(ci.x, cW[(k + 0) * D + lane], f0);
    f1 = fmaf(ci.y, cW[(k + 1) * D + lane], f1);
    f2 = fmaf(ci.z, cW[(k + 2) * D + lane], f2);
    f3 = fmaf(ci.w, cW[(k + 3) * D + lane], f3);
  }
#pragma unroll
  for (int k = 0; k < D; k += 4) {
    const float4 cr = *(const float4*)(sa + k);
    f0 = fmaf(cr.x, cW[(D + k + 0) * D + lane], f0);
    f1 = fmaf(cr.y, cW[(D + k + 1) * D + lane], f1);
    f2 = fmaf(cr.z, cW[(D + k + 2) * D + lane], f2);
    f3 = fmaf(cr.w, cW[(D + k + 3) * D + lane], f3);
  }
  const float f = fmaxf((f0 + f1) + (f2 + f3), 0.f);

  // ---- score = dot([user, f], oW) + ob ----
  const float sc = wave_sum64(fmaf(user, oW[lane], f * oW[D + lane]));
  if (lane == 0) out[b] = sc + ob[0];
}

// ================= fallback: exact R3 kernel (small/no workspace) ===========
__device__ __forceinline__ void load_grp(float (&buf)[GRP],
                                         const int* __restrict__ adjb,
                                         const float* __restrict__ ent_tab,
                                         int g, int lane) {
#pragma unroll
  for (int i = 0; i < GRP; ++i) {
    int t = adjb[g * GRP + i];
    t = t < 0 ? 0 : t;
    buf[i] = ent_tab[(long)t * D + lane];
  }
}

__device__ __forceinline__ void proc_grp(const float (&buf)[GRP],
                                         float Wn, float base,
                                         float& l0, float& l1, float& na) {
  float ex[GRP];
#pragma unroll
  for (int i = 0; i < GRP; ++i) {
    float t = wave_sum64(buf[i] * Wn) + base;
    t = t > 0.f ? t : 0.2f * t;
    ex[i] = __expf(t - 8.0f);
  }
#pragma unroll
  for (int i = 0; i < GRP; ++i) {
    if (i & 1) l1 += ex[i]; else l0 += ex[i];
    na = fmaf(ex[i], buf[i], na);
  }
}

__global__ __launch_bounds__(256, 4) void kgat_r3(
    const int* __restrict__ user_idx, const int* __restrict__ item_idx,
    const int* __restrict__ adj,
    const float* __restrict__ user_tab, const float* __restrict__ item_tab,
    const float* __restrict__ ent_tab,
    const float* __restrict__ attn_W, const float* __restrict__ attn_b,
    const float* __restrict__ W1, const float* __restrict__ b1,
    const float* __restrict__ W2, const float* __restrict__ b2,
    const float* __restrict__ cW, const float* __restrict__ cb,
    const float* __restrict__ oW, const float* __restrict__ ob,
    float* __restrict__ out, int B)
{
  const int lane = threadIdx.x & 63;
  const int wv   = threadIdx.x >> 6;
  const int b    = blockIdx.x * 4 + wv;
  if (b >= B) return;

  const float user = user_tab[(long)user_idx[b] * D + lane];
  const float oWu  = oW[lane];
  const float oWf  = oW[D + lane];
  const float item = item_tab[(long)item_idx[b] * D + lane];
  const float Wi   = attn_W[lane];
  const float Wn   = attn_W[D + lane];
  const float base = wave_sum64(item * Wi) + attn_b[0];
  const int* adjb = adj + b * NN;

  float na = 0.f, l0 = 0.f, l1 = 0.f;
  float A[GRP], Bv[GRP];
  load_grp(A,  adjb, ent_tab, 0, lane);
  load_grp(Bv, adjb, ent_tab, 1, lane);
  proc_grp(A,  Wn, base, l0, l1, na);
  load_grp(A,  adjb, ent_tab, 2, lane);
  proc_grp(Bv, Wn, base, l0, l1, na);
  load_grp(Bv, adjb, ent_tab, 3, lane);
  proc_grp(A,  Wn, base, l0, l1, na);
  load_grp(A,  adjb, ent_tab, 4, lane);
  proc_grp(Bv, Wn, base, l0, l1, na);
  proc_grp(A,  Wn, base, l0, l1, na);
  na /= (l0 + l1);

  float h0 = b1[lane], h1 = 0.f, h2 = 0.f, h3 = 0.f;
#pragma unroll
  for (int d = 0; d < D; d += 4) {
    h0 = fmaf(readlane_f(na, d + 0), W1[(d + 0) * D + lane], h0);
    h1 = fmaf(readlane_f(na, d + 1), W1[(d + 1) * D + lane], h1);
    h2 = fmaf(readlane_f(na, d + 2), W1[(d + 2) * D + lane], h2);
    h3 = fmaf(readlane_f(na, d + 3), W1[(d + 3) * D + lane], h3);
  }
  const float h = fmaxf((h0 + h1) + (h2 + h3), 0.f);

  float r0 = b2[lane], r1 = 0.f, r2 = 0.f, r3 = 0.f;
#pragma unroll
  for (int d = 0; d < D; d += 4) {
    r0 = fmaf(readlane_f(h, d + 0), W2[(d + 0) * D + lane], r0);
    r1 = fmaf(readlane_f(h, d + 1), W2[(d + 1) * D + lane], r1);
    r2 = fmaf(readlane_f(h, d + 2), W2[(d + 2) * D + lane], r2);
    r3 = fmaf(readlane_f(h, d + 3), W2[(d + 3) * D + lane], r3);
  }
  const float r = (r0 + r1) + (r2 + r3);

  float f0 = cb[lane], f1 = 0.f, f2 = 0.f, f3 = 0.f;
#pragma unroll
  for (int k = 0; k < D; k += 4) {
    f0 = fmaf(readlane_f(item, k + 0), cW[(k + 0) * D + lane], f0);
    f1 = fmaf(readlane_f(item, k + 1), cW[(k + 1) * D + lane], f1);
    f2 = fmaf(readlane_f(item, k + 2), cW[(k + 2) * D + lane], f2);
    f3 = fmaf(readlane_f(item, k + 3), cW[(k + 3) * D + lane], f3);
  }
#pragma unroll
  for (int k = 0; k < D; k += 4) {
    f0 = fmaf(readlane_f(r, k + 0), cW[(D + k + 0) * D + lane], f0);
    f1 = fmaf(readlane_f(r, k + 1), cW[(D + k + 1) * D + lane], f1);
    f2 = fmaf(readlane_f(r, k + 2), cW[(D + k + 2) * D + lane], f2);
    f3 = fmaf(readlane_f(r, k + 3), cW[(D + k + 3) * D + lane], f3);
  }
  const float f = fmaxf((f0 + f1) + (f2 + f3), 0.f);

  const float sc = wave_sum64(fmaf(user, oWu, f * oWf));
  if (lane == 0) out[b] = sc + ob[0];
}

extern "C" void kernel_launch(void* const* d_in, const int* in_sizes, int n_in,
                              void* d_out, int out_size, void* d_ws, size_t ws_size,
                              hipStream_t stream) {
  const int*   user_idx = (const int*)d_in[0];
  const int*   item_idx = (const int*)d_in[1];
  const int*   adj      = (const int*)d_in[2];
  const float* user_tab = (const float*)d_in[3];
  const float* item_tab = (const float*)d_in[4];
  const float* ent_tab  = (const float*)d_in[5];
  const float* attn_W   = (const float*)d_in[6];
  const float* attn_b   = (const float*)d_in[7];
  const float* W1       = (const float*)d_in[8];
  const float* b1       = (const float*)d_in[9];
  const float* W2       = (const float*)d_in[10];
  const float* b2       = (const float*)d_in[11];
  const float* cW       = (const float*)d_in[12];
  const float* cb       = (const float*)d_in[13];
  const float* oW       = (const float*)d_in[14];
  const float* ob       = (const float*)d_in[15];
  float* out = (float*)d_out;

  const int B    = in_sizes[0];
  const int rows = in_sizes[5] / D;               // entity count

  // ws layout: [proj f32][ent_bf bf16], 256B-aligned sections
  const size_t off_bf = ((size_t)rows * 4 + 255) & ~(size_t)255;
  const size_t need   = off_bf + (size_t)rows * D * 2;

  const int blocks = (B + 3) / 4;

  if (ws_size >= need) {
    float*    proj   = (float*)d_ws;
    ushort16* ent_bf = (ushort16*)((char*)d_ws + off_bf);
    const int waves   = (rows + GRP - 1) / GRP;
    const int pblocks = (waves + 3) / 4;
    ent_proj<<<pblocks, 256, 0, stream>>>(ent_tab, attn_W, proj, ent_bf, rows);
    kgat_fused<<<blocks, 256, 0, stream>>>(user_idx, item_idx, adj,
                                           user_tab, item_tab, ent_bf, proj,
                                           attn_W, attn_b, W1, b1, W2, b2,
                                           cW, cb, oW, ob, out, B);
  } else {
    kgat_r3<<<blocks, 256, 0, stream>>>(user_idx, item_idx, adj,
                                        user_tab, item_tab, ent_tab,
                                        attn_W, attn_b, W1, b1, W2, b2,
                                        cW, cb, oW, ob, out, B);
  }
}

// Round 13
// 72.587 us; speedup vs baseline: 1.1374x; 1.1374x over previous
//
#include <hip/hip_runtime.h>

#define NN 50
#define D 64
#define GRP 10

typedef unsigned int uint32;
typedef unsigned short ushort16;

__device__ __forceinline__ float wave_sum64(float x) {
#pragma unroll
  for (int off = 32; off > 0; off >>= 1)
    x += __shfl_xor(x, off, 64);
  return x;
}

__device__ __forceinline__ float readlane_f(float v, int l) {
  return __uint_as_float(__builtin_amdgcn_readlane(__float_as_uint(v), l));
}

__device__ __forceinline__ ushort16 f32_to_bf16(float f) {
  uint32 u = __float_as_uint(f);
  u += 0x7FFF + ((u >> 16) & 1);          // round-to-nearest-even
  return (ushort16)(u >> 16);
}
__device__ __forceinline__ float bf16_to_f32(ushort16 h) {
  return __uint_as_float(((uint32)h) << 16);
}

// ============ P: proj[e] = dot(ent[e], Wn); ent_bf = bf16(ent) ==============
__global__ __launch_bounds__(256, 4) void ent_proj(
    const float* __restrict__ ent_tab, const float* __restrict__ attn_W,
    float* __restrict__ proj, ushort16* __restrict__ ent_bf, int rows)
{
  const int  lane = threadIdx.x & 63;
  const long wave = (long)blockIdx.x * 4 + (threadIdx.x >> 6);
  const long base = wave * GRP;
  if (base >= rows) return;
  const float Wn = attn_W[D + lane];
  float v[GRP];
#pragma unroll
  for (int i = 0; i < GRP; ++i) {
    long r = base + i; if (r > rows - 1) r = rows - 1;
    v[i] = ent_tab[r * D + lane];           // coalesced, contiguous rows
  }
  float s[GRP];
#pragma unroll
  for (int i = 0; i < GRP; ++i)
    s[i] = wave_sum64(v[i] * Wn);           // 10 independent butterfly chains
#pragma unroll
  for (int i = 0; i < GRP; ++i) {
    const long r = base + i;
    if (r < rows) ent_bf[r * D + lane] = f32_to_bf16(v[i]);
  }
  if (lane == 0) {
#pragma unroll
    for (int i = 0; i < GRP; ++i)
      if (base + i < rows) proj[base + i] = s[i];
  }
}

// ============ fused attn + MLP, 50-deep prefetch, 256-VGPR budget ===========
__device__ __forceinline__ void load_grp_bf(float (&buf)[GRP],
                                            const int* __restrict__ adjb,
                                            const ushort16* __restrict__ ent_bf,
                                            int g, int lane) {
#pragma unroll
  for (int i = 0; i < GRP; ++i) {
    int t = adjb[g * GRP + i];              // wave-uniform -> s_load
    t = t < 0 ? 0 : t;
    buf[i] = bf16_to_f32(ent_bf[(long)t * D + lane]);   // 128B coalesced row
  }
}

__device__ __forceinline__ void acc_grp(const float (&buf)[GRP], float e, int g,
                                        float& na0, float& na1) {
#pragma unroll
  for (int i = 0; i < GRP; ++i) {
    const float w = readlane_f(e, g * GRP + i);   // compile-time lane index
    if (i & 1) na1 = fmaf(w, buf[i], na1);
    else       na0 = fmaf(w, buf[i], na0);
  }
}

// min-waves/EU = 2 -> VGPR cap 256: the 50 prefetched rows + transient
// address registers stay in HW regs (R12's (256,4) cap of 128 forced a
// 43 MB/dispatch scratch spill -- the whole regression).
__global__ __launch_bounds__(256, 2) void kgat_fused(
    const int* __restrict__ user_idx, const int* __restrict__ item_idx,
    const int* __restrict__ adj,
    const float* __restrict__ user_tab, const float* __restrict__ item_tab,
    const ushort16* __restrict__ ent_bf, const float* __restrict__ proj,
    const float* __restrict__ attn_W, const float* __restrict__ attn_b,
    const float* __restrict__ W1, const float* __restrict__ b1,
    const float* __restrict__ W2, const float* __restrict__ b2,
    const float* __restrict__ cW, const float* __restrict__ cb,
    const float* __restrict__ oW, const float* __restrict__ ob,
    float* __restrict__ out, int B)
{
  __shared__ __align__(16) float s_act[4 * D];   // per-wave activation bcast
  __shared__ __align__(16) float s_itm[4 * D];   // per-wave item bcast

  const int lane = threadIdx.x & 63;
  const int wv   = threadIdx.x >> 6;
  const int b    = blockIdx.x * 4 + wv;
  if (b >= B) return;
  float* sa = s_act + wv * D;
  float* si = s_itm + wv * D;

  const int* adjb = adj + (long)b * NN;

  // ---- score-path loads first (oldest in vmcnt order) ----
  const int myn = lane < NN ? lane : NN - 1;
  int mi = adjb[myn]; mi = mi < 0 ? 0 : mi;       // per-lane coalesced 200B
  const float pj   = proj[mi];                    // per-lane gather (L2-hot)
  const float user = user_tab[(long)user_idx[b] * D + lane];
  const float item = item_tab[(long)item_idx[b] * D + lane];

  // ---- deep prefetch: ALL 50 neighbor rows in flight (one round trip) ----
  float G0[GRP], G1[GRP], G2[GRP], G3[GRP], G4[GRP];
  load_grp_bf(G0, adjb, ent_bf, 0, lane);
  load_grp_bf(G1, adjb, ent_bf, 1, lane);
  load_grp_bf(G2, adjb, ent_bf, 2, lane);
  load_grp_bf(G3, adjb, ent_bf, 3, lane);
  load_grp_bf(G4, adjb, ent_bf, 4, lane);

  // ---- scores while gathers fly ----
  si[lane] = item;                                // wave-private, no barrier
  const float base = wave_sum64(item * attn_W[lane]) + attn_b[0];  // uniform
  float s = pj + base;
  s = s > 0.f ? s : 0.2f * s;                     // leaky_relu(0.2)
  // fixed-max softmax: scores are leaky_relu of ~unit-variance dots, bounded
  // well below 8 -> exp(s-8) can't overflow, denom can't underflow to 0.
  const float e = (lane < NN) ? __expf(s - 8.0f) : 0.f;
  const float denom = wave_sum64(e);

  // ---- weighted sum over the prefetched rows ----
  float na0 = 0.f, na1 = 0.f;
  acc_grp(G0, e, 0, na0, na1);
  acc_grp(G1, e, 1, na0, na1);
  acc_grp(G2, e, 2, na0, na1);
  acc_grp(G3, e, 3, na0, na1);
  acc_grp(G4, e, 4, na0, na1);
  const float na = (na0 + na1) / denom;

  // ---- h = relu(na @ W1 + b1): activations broadcast from LDS (b128,
  //      uniform address = conflict-free), weights coalesced from global ----
  sa[lane] = na;
  float h0 = b1[lane], h1 = 0.f, h2 = 0.f, h3 = 0.f;
#pragma unroll
  for (int d = 0; d < D; d += 4) {
    const float4 c = *(const float4*)(sa + d);
    h0 = fmaf(c.x, W1[(d + 0) * D + lane], h0);
    h1 = fmaf(c.y, W1[(d + 1) * D + lane], h1);
    h2 = fmaf(c.z, W1[(d + 2) * D + lane], h2);
    h3 = fmaf(c.w, W1[(d + 3) * D + lane], h3);
  }
  const float h = fmaxf((h0 + h1) + (h2 + h3), 0.f);

  // ---- r = h @ W2 + b2 ----
  sa[lane] = h;
  float r0 = b2[lane], r1 = 0.f, r2 = 0.f, r3 = 0.f;
#pragma unroll
  for (int d = 0; d < D; d += 4) {
    const float4 c = *(const float4*)(sa + d);
    r0 = fmaf(c.x, W2[(d + 0) * D + lane], r0);
    r1 = fmaf(c.y, W2[(d + 1) * D + lane], r1);
    r2 = fmaf(c.z, W2[(d + 2) * D + lane], r2);
    r3 = fmaf(c.w, W2[(d + 3) * D + lane], r3);
  }
  const float r = (r0 + r1) + (r2 + r3);

  // ---- f = relu([item, r] @ cW + cb) ----
  sa[lane] = r;
  float f0 = cb[lane], f1 = 0.f, f2 = 0.f, f3 = 0.f;
#pragma unroll
  for (int k = 0; k < D; k += 4) {
    const float4 ci = *(const float4*)(si + k);
    f0 = fmaf(ci.x, cW[(k + 0) * D + lane], f0);
    f1 = fmaf(ci.y, cW[(k + 1) * D + lane], f1);
    f2 = fmaf(ci.z, cW[(k + 2) * D + lane], f2);
    f3 = fmaf(ci.w, cW[(k + 3) * D + lane], f3);
  }
#pragma unroll
  for (int k = 0; k < D; k += 4) {
    const float4 cr = *(const float4*)(sa + k);
    f0 = fmaf(cr.x, cW[(D + k + 0) * D + lane], f0);
    f1 = fmaf(cr.y, cW[(D + k + 1) * D + lane], f1);
    f2 = fmaf(cr.z, cW[(D + k + 2) * D + lane], f2);
    f3 = fmaf(cr.w, cW[(D + k + 3) * D + lane], f3);
  }
  const float f = fmaxf((f0 + f1) + (f2 + f3), 0.f);

  // ---- score = dot([user, f], oW) + ob ----
  const float sc = wave_sum64(fmaf(user, oW[lane], f * oW[D + lane]));
  if (lane == 0) out[b] = sc + ob[0];
}

// ================= fallback: exact R3 kernel (small/no workspace) ===========
__device__ __forceinline__ void load_grp(float (&buf)[GRP],
                                         const int* __restrict__ adjb,
                                         const float* __restrict__ ent_tab,
                                         int g, int lane) {
#pragma unroll
  for (int i = 0; i < GRP; ++i) {
    int t = adjb[g * GRP + i];
    t = t < 0 ? 0 : t;
    buf[i] = ent_tab[(long)t * D + lane];
  }
}

__device__ __forceinline__ void proc_grp(const float (&buf)[GRP],
                                         float Wn, float base,
                                         float& l0, float& l1, float& na) {
  float ex[GRP];
#pragma unroll
  for (int i = 0; i < GRP; ++i) {
    float t = wave_sum64(buf[i] * Wn) + base;
    t = t > 0.f ? t : 0.2f * t;
    ex[i] = __expf(t - 8.0f);
  }
#pragma unroll
  for (int i = 0; i < GRP; ++i) {
    if (i & 1) l1 += ex[i]; else l0 += ex[i];
    na = fmaf(ex[i], buf[i], na);
  }
}

__global__ __launch_bounds__(256, 4) void kgat_r3(
    const int* __restrict__ user_idx, const int* __restrict__ item_idx,
    const int* __restrict__ adj,
    const float* __restrict__ user_tab, const float* __restrict__ item_tab,
    const float* __restrict__ ent_tab,
    const float* __restrict__ attn_W, const float* __restrict__ attn_b,
    const float* __restrict__ W1, const float* __restrict__ b1,
    const float* __restrict__ W2, const float* __restrict__ b2,
    const float* __restrict__ cW, const float* __restrict__ cb,
    const float* __restrict__ oW, const float* __restrict__ ob,
    float* __restrict__ out, int B)
{
  const int lane = threadIdx.x & 63;
  const int wv   = threadIdx.x >> 6;
  const int b    = blockIdx.x * 4 + wv;
  if (b >= B) return;

  const float user = user_tab[(long)user_idx[b] * D + lane];
  const float oWu  = oW[lane];
  const float oWf  = oW[D + lane];
  const float item = item_tab[(long)item_idx[b] * D + lane];
  const float Wi   = attn_W[lane];
  const float Wn   = attn_W[D + lane];
  const float base = wave_sum64(item * Wi) + attn_b[0];
  const int* adjb = adj + b * NN;

  float na = 0.f, l0 = 0.f, l1 = 0.f;
  float A[GRP], Bv[GRP];
  load_grp(A,  adjb, ent_tab, 0, lane);
  load_grp(Bv, adjb, ent_tab, 1, lane);
  proc_grp(A,  Wn, base, l0, l1, na);
  load_grp(A,  adjb, ent_tab, 2, lane);
  proc_grp(Bv, Wn, base, l0, l1, na);
  load_grp(Bv, adjb, ent_tab, 3, lane);
  proc_grp(A,  Wn, base, l0, l1, na);
  load_grp(A,  adjb, ent_tab, 4, lane);
  proc_grp(Bv, Wn, base, l0, l1, na);
  proc_grp(A,  Wn, base, l0, l1, na);
  na /= (l0 + l1);

  float h0 = b1[lane], h1 = 0.f, h2 = 0.f, h3 = 0.f;
#pragma unroll
  for (int d = 0; d < D; d += 4) {
    h0 = fmaf(readlane_f(na, d + 0), W1[(d + 0) * D + lane], h0);
    h1 = fmaf(readlane_f(na, d + 1), W1[(d + 1) * D + lane], h1);
    h2 = fmaf(readlane_f(na, d + 2), W1[(d + 2) * D + lane], h2);
    h3 = fmaf(readlane_f(na, d + 3), W1[(d + 3) * D + lane], h3);
  }
  const float h = fmaxf((h0 + h1) + (h2 + h3), 0.f);

  float r0 = b2[lane], r1 = 0.f, r2 = 0.f, r3 = 0.f;
#pragma unroll
  for (int d = 0; d < D; d += 4) {
    r0 = fmaf(readlane_f(h, d + 0), W2[(d + 0) * D + lane], r0);
    r1 = fmaf(readlane_f(h, d + 1), W2[(d + 1) * D + lane], r1);
    r2 = fmaf(readlane_f(h, d + 2), W2[(d + 2) * D + lane], r2);
    r3 = fmaf(readlane_f(h, d + 3), W2[(d + 3) * D + lane], r3);
  }
  const float r = (r0 + r1) + (r2 + r3);

  float f0 = cb[lane], f1 = 0.f, f2 = 0.f, f3 = 0.f;
#pragma unroll
  for (int k = 0; k < D; k += 4) {
    f0 = fmaf(readlane_f(item, k + 0), cW[(k + 0) * D + lane], f0);
    f1 = fmaf(readlane_f(item, k + 1), cW[(k + 1) * D + lane], f1);
    f2 = fmaf(readlane_f(item, k + 2), cW[(k + 2) * D + lane], f2);
    f3 = fmaf(readlane_f(item, k + 3), cW[(k + 3) * D + lane], f3);
  }
#pragma unroll
  for (int k = 0; k < D; k += 4) {
    f0 = fmaf(readlane_f(r, k + 0), cW[(D + k + 0) * D + lane], f0);
    f1 = fmaf(readlane_f(r, k + 1), cW[(D + k + 1) * D + lane], f1);
    f2 = fmaf(readlane_f(r, k + 2), cW[(D + k + 2) * D + lane], f2);
    f3 = fmaf(readlane_f(r, k + 3), cW[(D + k + 3) * D + lane], f3);
  }
  const float f = fmaxf((f0 + f1) + (f2 + f3), 0.f);

  const float sc = wave_sum64(fmaf(user, oWu, f * oWf));
  if (lane == 0) out[b] = sc + ob[0];
}

extern "C" void kernel_launch(void* const* d_in, const int* in_sizes, int n_in,
                              void* d_out, int out_size, void* d_ws, size_t ws_size,
                              hipStream_t stream) {
  const int*   user_idx = (const int*)d_in[0];
  const int*   item_idx = (const int*)d_in[1];
  const int*   adj      = (const int*)d_in[2];
  const float* user_tab = (const float*)d_in[3];
  const float* item_tab = (const float*)d_in[4];
  const float* ent_tab  = (const float*)d_in[5];
  const float* attn_W   = (const float*)d_in[6];
  const float* attn_b   = (const float*)d_in[7];
  const float* W1       = (const float*)d_in[8];
  const float* b1       = (const float*)d_in[9];
  const float* W2       = (const float*)d_in[10];
  const float* b2       = (const float*)d_in[11];
  const float* cW       = (const float*)d_in[12];
  const float* cb       = (const float*)d_in[13];
  const float* oW       = (const float*)d_in[14];
  const float* ob       = (const float*)d_in[15];
  float* out = (float*)d_out;

  const int B    = in_sizes[0];
  const int rows = in_sizes[5] / D;               // entity count

  // ws layout: [proj f32][ent_bf bf16], 256B-aligned sections
  const size_t off_bf = ((size_t)rows * 4 + 255) & ~(size_t)255;
  const size_t need   = off_bf + (size_t)rows * D * 2;

  const int blocks = (B + 3) / 4;

  if (ws_size >= need) {
    float*    proj   = (float*)d_ws;
    ushort16* ent_bf = (ushort16*)((char*)d_ws + off_bf);
    const int waves   = (rows + GRP - 1) / GRP;
    const int pblocks = (waves + 3) / 4;
    ent_proj<<<pblocks, 256, 0, stream>>>(ent_tab, attn_W, proj, ent_bf, rows);
    kgat_fused<<<blocks, 256, 0, stream>>>(user_idx, item_idx, adj,
                                           user_tab, item_tab, ent_bf, proj,
                                           attn_W, attn_b, W1, b1, W2, b2,
                                           cW, cb, oW, ob, out, B);
  } else {
    kgat_r3<<<blocks, 256, 0, stream>>>(user_idx, item_idx, adj,
                                        user_tab, item_tab, ent_tab,
                                        attn_W, attn_b, W1, b1, W2, b2,
                                        cW, cb, oW, ob, out, B);
  }
}

// Round 14
// 58.737 us; speedup vs baseline: 1.4056x; 1.2358x over previous
//
#include <hip/hip_runtime.h>

#define NN 50
#define D 64
#define GRP 10

typedef unsigned int uint32;
typedef unsigned short ushort16;

__device__ __forceinline__ float wave_sum64(float x) {
#pragma unroll
  for (int off = 32; off > 0; off >>= 1)
    x += __shfl_xor(x, off, 64);
  return x;
}

__device__ __forceinline__ float readlane_f(float v, int l) {
  return __uint_as_float(__builtin_amdgcn_readlane(__float_as_uint(v), l));
}

__device__ __forceinline__ ushort16 f32_to_bf16(float f) {
  uint32 u = __float_as_uint(f);
  u += 0x7FFF + ((u >> 16) & 1);          // round-to-nearest-even
  return (ushort16)(u >> 16);
}
__device__ __forceinline__ float bf16_to_f32(ushort16 h) {
  return __uint_as_float(((uint32)h) << 16);
}

// ============ P: proj[e] = dot(ent[e], Wn); ent_bf = bf16(ent) ==============
__global__ __launch_bounds__(256, 4) void ent_proj(
    const float* __restrict__ ent_tab, const float* __restrict__ attn_W,
    float* __restrict__ proj, ushort16* __restrict__ ent_bf, int rows)
{
  const int  lane = threadIdx.x & 63;
  const long wave = (long)blockIdx.x * 4 + (threadIdx.x >> 6);
  const long base = wave * GRP;
  if (base >= rows) return;
  const float Wn = attn_W[D + lane];
  float v[GRP];
#pragma unroll
  for (int i = 0; i < GRP; ++i) {
    long r = base + i; if (r > rows - 1) r = rows - 1;
    v[i] = ent_tab[r * D + lane];           // coalesced, contiguous rows
  }
  float s[GRP];
#pragma unroll
  for (int i = 0; i < GRP; ++i)
    s[i] = wave_sum64(v[i] * Wn);           // 10 independent butterfly chains
#pragma unroll
  for (int i = 0; i < GRP; ++i) {
    const long r = base + i;
    if (r < rows) ent_bf[r * D + lane] = f32_to_bf16(v[i]);
  }
  if (lane == 0) {
#pragma unroll
    for (int i = 0; i < GRP; ++i)
      if (base + i < rows) proj[base + i] = s[i];
  }
}

// ================= fused attn + MLP, 2 elements/wave ========================
__device__ __forceinline__ void load_grp_bf(float (&buf)[GRP],
                                            const int* __restrict__ adjb,
                                            const ushort16* __restrict__ ent_bf,
                                            int g, int lane) {
#pragma unroll
  for (int i = 0; i < GRP; ++i) {
    int t = adjb[g * GRP + i];              // wave-uniform -> s_load
    t = t < 0 ? 0 : t;
    buf[i] = bf16_to_f32(ent_bf[(long)t * D + lane]);   // 128B coalesced row
  }
}

__device__ __forceinline__ void acc_grp(const float (&buf)[GRP], float e, int g,
                                        float& na0, float& na1) {
#pragma unroll
  for (int i = 0; i < GRP; ++i) {
    const float w = readlane_f(e, g * GRP + i);   // compile-time lane index
    if (i & 1) na1 = fmaf(w, buf[i], na1);
    else       na0 = fmaf(w, buf[i], na0);
  }
}

// Full attention for one element (R13-proven: 50-row prefetch in named
// register arrays, per-lane proj score, fixed-max softmax). G arrays are
// local -> reused across the two sequential calls, no x2 register state.
__device__ __forceinline__ void attn_elem(
    int b, const int* __restrict__ adj,
    const ushort16* __restrict__ ent_bf, const float* __restrict__ proj,
    const int* __restrict__ user_idx, const int* __restrict__ item_idx,
    const float* __restrict__ user_tab, const float* __restrict__ item_tab,
    const float* __restrict__ attn_W, float ab, int lane,
    float& na_out, float& item_out, float& user_out)
{
  const int* adjb = adj + (long)b * NN;

  const int myn = lane < NN ? lane : NN - 1;
  int mi = adjb[myn]; mi = mi < 0 ? 0 : mi;       // per-lane coalesced 200B
  const float pj = proj[mi];                      // per-lane gather (L2-hot)
  user_out = user_tab[(long)user_idx[b] * D + lane];
  const float item = item_tab[(long)item_idx[b] * D + lane];

  float G0[GRP], G1[GRP], G2[GRP], G3[GRP], G4[GRP];
  load_grp_bf(G0, adjb, ent_bf, 0, lane);
  load_grp_bf(G1, adjb, ent_bf, 1, lane);
  load_grp_bf(G2, adjb, ent_bf, 2, lane);
  load_grp_bf(G3, adjb, ent_bf, 3, lane);
  load_grp_bf(G4, adjb, ent_bf, 4, lane);

  const float base = wave_sum64(item * attn_W[lane]) + ab;   // uniform
  float s = pj + base;
  s = s > 0.f ? s : 0.2f * s;                     // leaky_relu(0.2)
  // fixed-max softmax: scores are leaky_relu of ~unit-variance dots, bounded
  // well below 8 -> exp(s-8) can't overflow, denom can't underflow to 0.
  const float e = (lane < NN) ? __expf(s - 8.0f) : 0.f;
  const float denom = wave_sum64(e);

  float na0 = 0.f, na1 = 0.f;
  acc_grp(G0, e, 0, na0, na1);
  acc_grp(G1, e, 1, na0, na1);
  acc_grp(G2, e, 2, na0, na1);
  acc_grp(G3, e, 3, na0, na1);
  acc_grp(G4, e, 4, na0, na1);
  na_out = (na0 + na1) / denom;
  item_out = item;
}

__global__ __launch_bounds__(256, 2) void kgat_fused(
    const int* __restrict__ user_idx, const int* __restrict__ item_idx,
    const int* __restrict__ adj,
    const float* __restrict__ user_tab, const float* __restrict__ item_tab,
    const ushort16* __restrict__ ent_bf, const float* __restrict__ proj,
    const float* __restrict__ attn_W, const float* __restrict__ attn_b,
    const float* __restrict__ W1, const float* __restrict__ b1,
    const float* __restrict__ W2, const float* __restrict__ b2,
    const float* __restrict__ cW, const float* __restrict__ cb,
    const float* __restrict__ oW, const float* __restrict__ ob,
    float* __restrict__ out, int B)
{
  __shared__ __align__(16) float s_a0[4 * D], s_a1[4 * D];  // act broadcasts
  __shared__ __align__(16) float s_i0[4 * D], s_i1[4 * D];  // item broadcasts

  const int lane = threadIdx.x & 63;
  const int wv   = threadIdx.x >> 6;
  const int bA   = (blockIdx.x * 4 + wv) * 2;     // 2 elements per wave
  if (bA >= B) return;
  const int bB   = bA + 1 < B ? bA + 1 : bA;      // B even in practice
  float* sa0 = s_a0 + wv * D;
  float* sa1 = s_a1 + wv * D;
  float* si0 = s_i0 + wv * D;
  float* si1 = s_i1 + wv * D;

  const float ab = attn_b[0];

  // ---- attention, sequential (G registers reused; ~constant pressure) ----
  float naA, itA, usA, naB, itB, usB;
  attn_elem(bA, adj, ent_bf, proj, user_idx, item_idx,
            user_tab, item_tab, attn_W, ab, lane, naA, itA, usA);
  attn_elem(bB, adj, ent_bf, proj, user_idx, item_idx,
            user_tab, item_tab, attn_W, ab, lane, naB, itB, usB);

  // ---- MLP: every weight column load feeds BOTH elements ----
  sa0[lane] = naA; sa1[lane] = naB;               // wave-private, no barrier
  si0[lane] = itA; si1[lane] = itB;

  // h = relu(na @ W1 + b1)
  const float b1v = b1[lane];
  float hA0 = b1v, hA1 = 0.f, hA2 = 0.f, hA3 = 0.f;
  float hB0 = b1v, hB1 = 0.f, hB2 = 0.f, hB3 = 0.f;
#pragma unroll
  for (int d = 0; d < D; d += 4) {
    const float4 cA = *(const float4*)(sa0 + d);
    const float4 cB = *(const float4*)(sa1 + d);
    const float w0 = W1[(d + 0) * D + lane];
    const float w1 = W1[(d + 1) * D + lane];
    const float w2 = W1[(d + 2) * D + lane];
    const float w3 = W1[(d + 3) * D + lane];
    hA0 = fmaf(cA.x, w0, hA0); hB0 = fmaf(cB.x, w0, hB0);
    hA1 = fmaf(cA.y, w1, hA1); hB1 = fmaf(cB.y, w1, hB1);
    hA2 = fmaf(cA.z, w2, hA2); hB2 = fmaf(cB.z, w2, hB2);
    hA3 = fmaf(cA.w, w3, hA3); hB3 = fmaf(cB.w, w3, hB3);
  }
  const float hA = fmaxf((hA0 + hA1) + (hA2 + hA3), 0.f);
  const float hB = fmaxf((hB0 + hB1) + (hB2 + hB3), 0.f);

  // r = h @ W2 + b2
  sa0[lane] = hA; sa1[lane] = hB;
  const float b2v = b2[lane];
  float rA0 = b2v, rA1 = 0.f, rA2 = 0.f, rA3 = 0.f;
  float rB0 = b2v, rB1 = 0.f, rB2 = 0.f, rB3 = 0.f;
#pragma unroll
  for (int d = 0; d < D; d += 4) {
    const float4 cA = *(const float4*)(sa0 + d);
    const float4 cB = *(const float4*)(sa1 + d);
    const float w0 = W2[(d + 0) * D + lane];
    const float w1 = W2[(d + 1) * D + lane];
    const float w2 = W2[(d + 2) * D + lane];
    const float w3 = W2[(d + 3) * D + lane];
    rA0 = fmaf(cA.x, w0, rA0); rB0 = fmaf(cB.x, w0, rB0);
    rA1 = fmaf(cA.y, w1, rA1); rB1 = fmaf(cB.y, w1, rB1);
    rA2 = fmaf(cA.z, w2, rA2); rB2 = fmaf(cB.z, w2, rB2);
    rA3 = fmaf(cA.w, w3, rA3); rB3 = fmaf(cB.w, w3, rB3);
  }
  const float rA = (rA0 + rA1) + (rA2 + rA3);
  const float rB = (rB0 + rB1) + (rB2 + rB3);

  // f = relu([item, r] @ cW + cb)
  sa0[lane] = rA; sa1[lane] = rB;
  const float cbv = cb[lane];
  float fA0 = cbv, fA1 = 0.f, fA2 = 0.f, fA3 = 0.f;
  float fB0 = cbv, fB1 = 0.f, fB2 = 0.f, fB3 = 0.f;
#pragma unroll
  for (int k = 0; k < D; k += 4) {
    const float4 cA = *(const float4*)(si0 + k);
    const float4 cB = *(const float4*)(si1 + k);
    const float w0 = cW[(k + 0) * D + lane];
    const float w1 = cW[(k + 1) * D + lane];
    const float w2 = cW[(k + 2) * D + lane];
    const float w3 = cW[(k + 3) * D + lane];
    fA0 = fmaf(cA.x, w0, fA0); fB0 = fmaf(cB.x, w0, fB0);
    fA1 = fmaf(cA.y, w1, fA1); fB1 = fmaf(cB.y, w1, fB1);
    fA2 = fmaf(cA.z, w2, fA2); fB2 = fmaf(cB.z, w2, fB2);
    fA3 = fmaf(cA.w, w3, fA3); fB3 = fmaf(cB.w, w3, fB3);
  }
#pragma unroll
  for (int k = 0; k < D; k += 4) {
    const float4 cA = *(const float4*)(sa0 + k);
    const float4 cB = *(const float4*)(sa1 + k);
    const float w0 = cW[(D + k + 0) * D + lane];
    const float w1 = cW[(D + k + 1) * D + lane];
    const float w2 = cW[(D + k + 2) * D + lane];
    const float w3 = cW[(D + k + 3) * D + lane];
    fA0 = fmaf(cA.x, w0, fA0); fB0 = fmaf(cB.x, w0, fB0);
    fA1 = fmaf(cA.y, w1, fA1); fB1 = fmaf(cB.y, w1, fB1);
    fA2 = fmaf(cA.z, w2, fA2); fB2 = fmaf(cB.z, w2, fB2);
    fA3 = fmaf(cA.w, w3, fA3); fB3 = fmaf(cB.w, w3, fB3);
  }
  const float fA = fmaxf((fA0 + fA1) + (fA2 + fA3), 0.f);
  const float fB = fmaxf((fB0 + fB1) + (fB2 + fB3), 0.f);

  // score = dot([user, f], oW) + ob
  const float oWu = oW[lane];
  const float oWf = oW[D + lane];
  const float ob0 = ob[0];
  const float scA = wave_sum64(fmaf(usA, oWu, fA * oWf));
  const float scB = wave_sum64(fmaf(usB, oWu, fB * oWf));
  if (lane == 0) {
    out[bA] = scA + ob0;
    if (bB != bA) out[bB] = scB + ob0;
  }
}

// ================= fallback: exact R3 kernel (small/no workspace) ===========
__device__ __forceinline__ void load_grp(float (&buf)[GRP],
                                         const int* __restrict__ adjb,
                                         const float* __restrict__ ent_tab,
                                         int g, int lane) {
#pragma unroll
  for (int i = 0; i < GRP; ++i) {
    int t = adjb[g * GRP + i];
    t = t < 0 ? 0 : t;
    buf[i] = ent_tab[(long)t * D + lane];
  }
}

__device__ __forceinline__ void proc_grp(const float (&buf)[GRP],
                                         float Wn, float base,
                                         float& l0, float& l1, float& na) {
  float ex[GRP];
#pragma unroll
  for (int i = 0; i < GRP; ++i) {
    float t = wave_sum64(buf[i] * Wn) + base;
    t = t > 0.f ? t : 0.2f * t;
    ex[i] = __expf(t - 8.0f);
  }
#pragma unroll
  for (int i = 0; i < GRP; ++i) {
    if (i & 1) l1 += ex[i]; else l0 += ex[i];
    na = fmaf(ex[i], buf[i], na);
  }
}

__global__ __launch_bounds__(256, 4) void kgat_r3(
    const int* __restrict__ user_idx, const int* __restrict__ item_idx,
    const int* __restrict__ adj,
    const float* __restrict__ user_tab, const float* __restrict__ item_tab,
    const float* __restrict__ ent_tab,
    const float* __restrict__ attn_W, const float* __restrict__ attn_b,
    const float* __restrict__ W1, const float* __restrict__ b1,
    const float* __restrict__ W2, const float* __restrict__ b2,
    const float* __restrict__ cW, const float* __restrict__ cb,
    const float* __restrict__ oW, const float* __restrict__ ob,
    float* __restrict__ out, int B)
{
  const int lane = threadIdx.x & 63;
  const int wv   = threadIdx.x >> 6;
  const int b    = blockIdx.x * 4 + wv;
  if (b >= B) return;

  const float user = user_tab[(long)user_idx[b] * D + lane];
  const float oWu  = oW[lane];
  const float oWf  = oW[D + lane];
  const float item = item_tab[(long)item_idx[b] * D + lane];
  const float Wi   = attn_W[lane];
  const float Wn   = attn_W[D + lane];
  const float base = wave_sum64(item * Wi) + attn_b[0];
  const int* adjb = adj + b * NN;

  float na = 0.f, l0 = 0.f, l1 = 0.f;
  float A[GRP], Bv[GRP];
  load_grp(A,  adjb, ent_tab, 0, lane);
  load_grp(Bv, adjb, ent_tab, 1, lane);
  proc_grp(A,  Wn, base, l0, l1, na);
  load_grp(A,  adjb, ent_tab, 2, lane);
  proc_grp(Bv, Wn, base, l0, l1, na);
  load_grp(Bv, adjb, ent_tab, 3, lane);
  proc_grp(A,  Wn, base, l0, l1, na);
  load_grp(A,  adjb, ent_tab, 4, lane);
  proc_grp(Bv, Wn, base, l0, l1, na);
  proc_grp(A,  Wn, base, l0, l1, na);
  na /= (l0 + l1);

  float h0 = b1[lane], h1 = 0.f, h2 = 0.f, h3 = 0.f;
#pragma unroll
  for (int d = 0; d < D; d += 4) {
    h0 = fmaf(readlane_f(na, d + 0), W1[(d + 0) * D + lane], h0);
    h1 = fmaf(readlane_f(na, d + 1), W1[(d + 1) * D + lane], h1);
    h2 = fmaf(readlane_f(na, d + 2), W1[(d + 2) * D + lane], h2);
    h3 = fmaf(readlane_f(na, d + 3), W1[(d + 3) * D + lane], h3);
  }
  const float h = fmaxf((h0 + h1) + (h2 + h3), 0.f);

  float r0 = b2[lane], r1 = 0.f, r2 = 0.f, r3 = 0.f;
#pragma unroll
  for (int d = 0; d < D; d += 4) {
    r0 = fmaf(readlane_f(h, d + 0), W2[(d + 0) * D + lane], r0);
    r1 = fmaf(readlane_f(h, d + 1), W2[(d + 1) * D + lane], r1);
    r2 = fmaf(readlane_f(h, d + 2), W2[(d + 2) * D + lane], r2);
    r3 = fmaf(readlane_f(h, d + 3), W2[(d + 3) * D + lane], r3);
  }
  const float r = (r0 + r1) + (r2 + r3);

  float f0 = cb[lane], f1 = 0.f, f2 = 0.f, f3 = 0.f;
#pragma unroll
  for (int k = 0; k < D; k += 4) {
    f0 = fmaf(readlane_f(item, k + 0), cW[(k + 0) * D + lane], f0);
    f1 = fmaf(readlane_f(item, k + 1), cW[(k + 1) * D + lane], f1);
    f2 = fmaf(readlane_f(item, k + 2), cW[(k + 2) * D + lane], f2);
    f3 = fmaf(readlane_f(item, k + 3), cW[(k + 3) * D + lane], f3);
  }
#pragma unroll
  for (int k = 0; k < D; k += 4) {
    f0 = fmaf(readlane_f(r, k + 0), cW[(D + k + 0) * D + lane], f0);
    f1 = fmaf(readlane_f(r, k + 1), cW[(D + k + 1) * D + lane], f1);
    f2 = fmaf(readlane_f(r, k + 2), cW[(D + k + 2) * D + lane], f2);
    f3 = fmaf(readlane_f(r, k + 3), cW[(D + k + 3) * D + lane], f3);
  }
  const float f = fmaxf((f0 + f1) + (f2 + f3), 0.f);

  const float sc = wave_sum64(fmaf(user, oWu, f * oWf));
  if (lane == 0) out[b] = sc + ob[0];
}

extern "C" void kernel_launch(void* const* d_in, const int* in_sizes, int n_in,
                              void* d_out, int out_size, void* d_ws, size_t ws_size,
                              hipStream_t stream) {
  const int*   user_idx = (const int*)d_in[0];
  const int*   item_idx = (const int*)d_in[1];
  const int*   adj      = (const int*)d_in[2];
  const float* user_tab = (const float*)d_in[3];
  const float* item_tab = (const float*)d_in[4];
  const float* ent_tab  = (const float*)d_in[5];
  const float* attn_W   = (const float*)d_in[6];
  const float* attn_b   = (const float*)d_in[7];
  const float* W1       = (const float*)d_in[8];
  const float* b1       = (const float*)d_in[9];
  const float* W2       = (const float*)d_in[10];
  const float* b2       = (const float*)d_in[11];
  const float* cW       = (const float*)d_in[12];
  const float* cb       = (const float*)d_in[13];
  const float* oW       = (const float*)d_in[14];
  const float* ob       = (const float*)d_in[15];
  float* out = (float*)d_out;

  const int B    = in_sizes[0];
  const int rows = in_sizes[5] / D;               // entity count

  // ws layout: [proj f32][ent_bf bf16], 256B-aligned sections
  const size_t off_bf = ((size_t)rows * 4 + 255) & ~(size_t)255;
  const size_t need   = off_bf + (size_t)rows * D * 2;

  if (ws_size >= need) {
    float*    proj   = (float*)d_ws;
    ushort16* ent_bf = (ushort16*)((char*)d_ws + off_bf);
    const int waves   = (rows + GRP - 1) / GRP;
    const int pblocks = (waves + 3) / 4;
    const int fblocks = (B + 8 - 1) / 8;          // 4 waves x 2 elements
    ent_proj<<<pblocks, 256, 0, stream>>>(ent_tab, attn_W, proj, ent_bf, rows);
    kgat_fused<<<fblocks, 256, 0, stream>>>(user_idx, item_idx, adj,
                                            user_tab, item_tab, ent_bf, proj,
                                            attn_W, attn_b, W1, b1, W2, b2,
                                            cW, cb, oW, ob, out, B);
  } else {
    const int blocks = (B + 3) / 4;
    kgat_r3<<<blocks, 256, 0, stream>>>(user_idx, item_idx, adj,
                                        user_tab, item_tab, ent_tab,
                                        attn_W, attn_b, W1, b1, W2, b2,
                                        cW, cb, oW, ob, out, B);
  }
}